// Round 15
// baseline (145.850 us; speedup 1.0000x reference)
//
#include <hip/hip_runtime.h>
#include <hip/hip_bf16.h>

// MultiHeadAttention: x(2,2048,1024) fp32 -> out(2,2048,1024) fp32
// Pipeline: cvt (weights only); QKV GEMM reads x fp32 directly (A reg-staged cvt,
// W via global_load_lds; 32x32x16 mfma; XCD-swizzled) -> q,k,v^T; flash attn
// (8 waves = 4 row-groups x 2 KV-halves, in-LDS merge, XCD swizzle); out GEMM.
//
// ws layout:
//   [0,8M)    attn-out (bf16)
//   [8,16M)   wqkv bf16 (6MB)
//   [16,24M)  q   [24,32M) k   [32,40M) vt   [40,42M) wout bf16

typedef __bf16 bf16x8 __attribute__((ext_vector_type(8)));
typedef __bf16 bf16x4 __attribute__((ext_vector_type(4)));
typedef short short4v __attribute__((ext_vector_type(4)));
typedef float f32x4 __attribute__((ext_vector_type(4)));
typedef float f32x16 __attribute__((ext_vector_type(16)));

#define QSCALE 0.18033688011112042f  // 0.125 * log2(e): QK^T lands in log2 domain

__device__ __forceinline__ unsigned short bfbits(float f) {
    union { __bf16 h; unsigned short u; } cv;
    cv.h = (__bf16)f;
    return cv.u;
}

__device__ __forceinline__ f32x4 mfma16(bf16x4 a, bf16x4 b, f32x4 c) {
#if __has_builtin(__builtin_amdgcn_mfma_f32_16x16x16bf16_1k)
    union { bf16x4 h; short4v s; } ua, ub;
    ua.h = a; ub.h = b;
    return __builtin_amdgcn_mfma_f32_16x16x16bf16_1k(ua.s, ub.s, c, 0, 0, 0);
#else
    f32x4 d = c;
    asm volatile("v_mfma_f32_16x16x16_bf16 %0, %1, %2, %0"
                 : "+v"(d) : "v"(a), "v"(b));
    return d;
#endif
}

__device__ __forceinline__ void gl_lds16(const void* g, void* l) {
    __builtin_amdgcn_global_load_lds(
        (__attribute__((address_space(1))) const unsigned int*)g,
        (__attribute__((address_space(3))) unsigned int*)l, 16, 0, 0);
}

// Weights-only bf16 conversion: qkv_w (786432 f4) + out_w (262144 f4).
__global__ void cvt_w(const float4* __restrict__ wq,
                      const float4* __restrict__ wo,
                      ushort4* __restrict__ d1,
                      ushort4* __restrict__ d2) {
    int i = blockIdx.x * blockDim.x + threadIdx.x;
    const int stride = gridDim.x * blockDim.x;
    for (; i < 1048576; i += stride) {
        float4 f;
        ushort4* d;
        int k;
        if (i < 786432) { f = wq[i];          d = d1; k = i; }
        else            { f = wo[i - 786432]; d = d2; k = i - 786432; }
        ushort4 o;
        o.x = bfbits(f.x); o.y = bfbits(f.y); o.z = bfbits(f.z); o.w = bfbits(f.w);
        d[k] = o;
    }
}

// C = A(M x 1024) @ W(N x 1024)^T + bias. 128x128 block tile, 4 waves (2x2),
// each wave 64x64 via 2x2 mfma_f32_32x32x16_bf16. m97-style staging (BK=64,
// chunk^(row&7) swizzle, 2-barrier K-loop). XCD-swizzled block mapping
// (bx-minor: each XCD owns contiguous W-panels; requires gridDim.x==32, nb%8==0).
// MODE 0: A = fp32 x, reg-staged with on-the-fly bf16 cvt (identical RNE rounding
// to a standalone cvt kernel) + swizzled ds_write; N=3072, scatter q/k/vt.
// MODE 1: A = bf16 (attn out), global_load_lds staging; N=1024, fp32 out.
template<int MODE>
__global__ __launch_bounds__(256, 3) void gemm_mfma(
    const float* __restrict__ Af,
    const unsigned short* __restrict__ Ab,
    const unsigned short* __restrict__ W,
    const float* __restrict__ bias,
    unsigned short* __restrict__ qo,
    unsigned short* __restrict__ ko,
    unsigned short* __restrict__ vto,
    float* __restrict__ fo) {
    __shared__ __attribute__((aligned(128))) unsigned char smem[32768];
    const int lane = threadIdx.x & 63;
    const int w = threadIdx.x >> 6;
    const int c5 = lane & 31, hi = lane >> 5;
    const int wr = w >> 1, wc = w & 1;

    // XCD-aware remap (bijective: nb % 8 == 0); gridDim.x == 32.
    const int nb = gridDim.x * gridDim.y;
    const int d = blockIdx.x + (blockIdx.y << 5);
    const int wv = (d & 7) * (nb >> 3) + (d >> 3);
    const int row0 = (wv & 31) * 128;
    const int col0 = (wv >> 5) * 128;

    const int rloc = lane >> 3;                      // 0..7
    const int csrc = ((lane & 7) ^ rloc) * 8;        // pre-swizzled source chunk (elements)

    f32x16 acc[2][2] = {};

    const int ra = wr * 64 + c5;                     // A rows for mi=0 (+32 for mi=1)
    const int rb = wc * 64 + c5;
    const int swa = ra & 7, swb = rb & 7;            // (r+32)&7 == r&7

    for (int kt = 0; kt < 1024; kt += 64) {
        #pragma unroll
        for (int i = 0; i < 4; ++i) {
            const int r = i * 32 + w * 8 + rloc;
            if (MODE == 0) {
                // fp32 A: load 8 floats, cvt to bf16, swizzled ds_write_b128
                const float* src = Af + (size_t)(row0 + r) * 1024 + kt + (lane & 7) * 8;
                const float4 f0 = *(const float4*)(src);
                const float4 f1 = *(const float4*)(src + 4);
                bf16x8 v;
                v[0] = (__bf16)f0.x; v[1] = (__bf16)f0.y;
                v[2] = (__bf16)f0.z; v[3] = (__bf16)f0.w;
                v[4] = (__bf16)f1.x; v[5] = (__bf16)f1.y;
                v[6] = (__bf16)f1.z; v[7] = (__bf16)f1.w;
                *(bf16x8*)(smem + i * 4096 + (w * 8 + rloc) * 128 + csrc * 2) = v;
            } else {
                gl_lds16(Ab + (size_t)(row0 + r) * 1024 + kt + csrc,
                         smem + i * 4096 + w * 1024);
            }
            gl_lds16(W + (size_t)(col0 + r) * 1024 + kt + csrc,
                     smem + 16384 + i * 4096 + w * 1024);
        }
        __syncthreads();

        #pragma unroll
        for (int ks = 0; ks < 4; ++ks) {
            const int ch_a = ((2 * ks + hi) ^ swa) * 16;
            const int ch_b = ((2 * ks + hi) ^ swb) * 16;
            bf16x8 a0 = *(const bf16x8*)(smem + ra * 128 + ch_a);
            bf16x8 a1 = *(const bf16x8*)(smem + (ra + 32) * 128 + ch_a);
            bf16x8 b0 = *(const bf16x8*)(smem + 16384 + rb * 128 + ch_b);
            bf16x8 b1 = *(const bf16x8*)(smem + 16384 + (rb + 32) * 128 + ch_b);
            acc[0][0] = __builtin_amdgcn_mfma_f32_32x32x16_bf16(a0, b0, acc[0][0], 0, 0, 0);
            acc[0][1] = __builtin_amdgcn_mfma_f32_32x32x16_bf16(a0, b1, acc[0][1], 0, 0, 0);
            acc[1][0] = __builtin_amdgcn_mfma_f32_32x32x16_bf16(a1, b0, acc[1][0], 0, 0, 0);
            acc[1][1] = __builtin_amdgcn_mfma_f32_32x32x16_bf16(a1, b1, acc[1][1], 0, 0, 0);
        }
        __syncthreads();
    }

    #pragma unroll
    for (int mi = 0; mi < 2; ++mi) {
        #pragma unroll
        for (int ni = 0; ni < 2; ++ni) {
            const int col = col0 + wc * 64 + ni * 32 + c5;
            const float bv = bias[col];
            #pragma unroll
            for (int r = 0; r < 16; ++r) {
                const int row = row0 + wr * 64 + mi * 32 + (r & 3) + 8 * (r >> 2) + 4 * hi;
                float v = acc[mi][ni][r] + bv;
                if (MODE == 1) {
                    fo[(size_t)row * 1024 + col] = v;
                } else {
                    const int sec = col >> 10;          // 0=q 1=k 2=v
                    const int dd = col & 1023;
                    const int h = dd >> 6, dk = dd & 63;
                    const int b_ = row >> 11, n = row & 2047;
                    const int bh = b_ * 16 + h;
                    if (sec == 0)
                        qo[((size_t)(bh * 2048 + n) << 6) + dk] = bfbits(v * QSCALE);
                    else if (sec == 1)
                        ko[((size_t)(bh * 2048 + n) << 6) + dk] = bfbits(v);
                    else
                        vto[(size_t)(bh * 64 + dk) * 2048 + n] = bfbits(v);
                }
            }
        }
    }
}

// Flash attention, split-KV internalized: 8 waves = 4 row-groups (hw) x 2 KV
// halves (hz); in-LDS merge; XCD swizzle. (Unchanged from R14 — proven.)
__global__ __launch_bounds__(512, 4) void attn_flash(
    const unsigned short* __restrict__ Q,
    const unsigned short* __restrict__ K,
    const unsigned short* __restrict__ Vt,
    unsigned short* __restrict__ O) {
    __shared__ __attribute__((aligned(128))) unsigned char smem[65536];
    const int lane = threadIdx.x & 63;
    const int w = threadIdx.x >> 6;          // 0..7
    const int hw = w & 3;                    // row-group
    const int hz = w >> 2;                   // KV half
    const int g = lane >> 4, c = lane & 15;
    const int c7 = c & 7;

    const int d = blockIdx.x + 16 * blockIdx.y;
    const int wv = (d & 7) * 64 + (d >> 3);
    const int bx = wv & 15;
    const int bh = wv >> 4;

    const int q0 = bx * 128 + hw * 32;
    const unsigned short* Qb = Q + (size_t)bh * 2048 * 64;
    const unsigned short* Kb = K + (size_t)bh * 2048 * 64;
    const unsigned short* Vb = Vt + (size_t)bh * 64 * 2048;

    const int rloc = lane >> 3;
    const int csrc = ((lane & 7) ^ (rloc & 7)) * 8;

    const int chunkKV0 = ((0 + g) ^ c7) * 16;
    const int chunkKV1 = ((4 + g) ^ c7) * 16;
    const int ghalf = g >> 1;
    const int gsub = (g & 1) * 8;

    unsigned char* Sbase = smem + hz * 32768;

    bf16x8 aq[2][2];
    #pragma unroll
    for (int qg = 0; qg < 2; ++qg)
        #pragma unroll
        for (int ks = 0; ks < 2; ++ks)
            aq[qg][ks] = *(const bf16x8*)(Qb + (size_t)(q0 + qg * 16 + c) * 64 + ks * 32 + 8 * g);

    f32x4 oa[4] = {}, ob[4] = {};
    f32x4 la = {}, lb = {};
    float ma = -1e30f, mb = -1e30f;

    bf16x4 ones4;
    #pragma unroll
    for (int i = 0; i < 4; ++i) ones4[i] = (__bf16)1.0f;

    const int gt0 = hz * 16;

    #pragma unroll
    for (int tt = 0; tt < 2; ++tt) {
        const int t = 2 * hw + tt;
        const int row = 8 * t + rloc;
        gl_lds16(Kb + (size_t)(gt0 * 64 + row) * 64 + csrc, Sbase + t * 1024);
        gl_lds16(Vb + (size_t)row * 2048 + gt0 * 64 + csrc, Sbase + 16384 + t * 1024);
    }
    __syncthreads();

    for (int t = 0; t < 16; ++t) {
        const int cur = t & 1;
        if (t + 1 < 16) {
            const int nb = cur ^ 1;
            const int gt = gt0 + t + 1;
            #pragma unroll
            for (int tt = 0; tt < 2; ++tt) {
                const int ti = 2 * hw + tt;
                const int row = 8 * ti + rloc;
                gl_lds16(Kb + (size_t)(gt * 64 + row) * 64 + csrc,
                         Sbase + nb * 8192 + ti * 1024);
                gl_lds16(Vb + (size_t)row * 2048 + gt * 64 + csrc,
                         Sbase + 16384 + nb * 8192 + ti * 1024);
            }
        }

        const unsigned char* Kt = Sbase + cur * 8192;
        const unsigned char* Vtb = Sbase + 16384 + cur * 8192;

        f32x4 sa[4] = {}, sb[4] = {};
        __builtin_amdgcn_s_setprio(1);
        #pragma unroll
        for (int nj = 0; nj < 4; ++nj) {
            bf16x8 bk0 = *(const bf16x8*)(Kt + nj * 2048 + c * 128 + chunkKV0);
            bf16x8 bk1 = *(const bf16x8*)(Kt + nj * 2048 + c * 128 + chunkKV1);
            sa[nj] = __builtin_amdgcn_mfma_f32_16x16x32_bf16(bk0, aq[0][0], sa[nj], 0, 0, 0);
            sa[nj] = __builtin_amdgcn_mfma_f32_16x16x32_bf16(bk1, aq[0][1], sa[nj], 0, 0, 0);
            sb[nj] = __builtin_amdgcn_mfma_f32_16x16x32_bf16(bk0, aq[1][0], sb[nj], 0, 0, 0);
            sb[nj] = __builtin_amdgcn_mfma_f32_16x16x32_bf16(bk1, aq[1][1], sb[nj], 0, 0, 0);
        }
        __builtin_amdgcn_s_setprio(0);

        float pa, pb;
        {
            float a0 = fmaxf(fmaxf(sa[0][0], sa[0][1]), fmaxf(sa[0][2], sa[0][3]));
            float a1 = fmaxf(fmaxf(sa[1][0], sa[1][1]), fmaxf(sa[1][2], sa[1][3]));
            float a2 = fmaxf(fmaxf(sa[2][0], sa[2][1]), fmaxf(sa[2][2], sa[2][3]));
            float a3 = fmaxf(fmaxf(sa[3][0], sa[3][1]), fmaxf(sa[3][2], sa[3][3]));
            pa = fmaxf(fmaxf(a0, a1), fmaxf(a2, a3));
            float b0 = fmaxf(fmaxf(sb[0][0], sb[0][1]), fmaxf(sb[0][2], sb[0][3]));
            float b1 = fmaxf(fmaxf(sb[1][0], sb[1][1]), fmaxf(sb[1][2], sb[1][3]));
            float b2 = fmaxf(fmaxf(sb[2][0], sb[2][1]), fmaxf(sb[2][2], sb[2][3]));
            float b3 = fmaxf(fmaxf(sb[3][0], sb[3][1]), fmaxf(sb[3][2], sb[3][3]));
            pb = fmaxf(fmaxf(b0, b1), fmaxf(b2, b3));
        }

        const bool trig = (pa > ma + 8.f) || (pb > mb + 8.f);
        if (__any((int)trig)) {
            float rm = pa;
            rm = fmaxf(rm, __shfl_xor(rm, 16));
            rm = fmaxf(rm, __shfl_xor(rm, 32));
            float mnew = fmaxf(ma, rm);
            float sc = __builtin_amdgcn_exp2f(ma - mnew);
            ma = mnew;
            #pragma unroll
            for (int j = 0; j < 4; ++j) {
                const float scj = __shfl(sc, 4 * g + j);
                la[j] *= scj;
                #pragma unroll
                for (int ni = 0; ni < 4; ++ni) oa[ni][j] *= scj;
            }
            rm = pb;
            rm = fmaxf(rm, __shfl_xor(rm, 16));
            rm = fmaxf(rm, __shfl_xor(rm, 32));
            mnew = fmaxf(mb, rm);
            sc = __builtin_amdgcn_exp2f(mb - mnew);
            mb = mnew;
            #pragma unroll
            for (int j = 0; j < 4; ++j) {
                const float scj = __shfl(sc, 4 * g + j);
                lb[j] *= scj;
                #pragma unroll
                for (int ni = 0; ni < 4; ++ni) ob[ni][j] *= scj;
            }
        }

        bf16x4 qa_[4], qb_[4];
        #pragma unroll
        for (int nj = 0; nj < 4; ++nj)
            #pragma unroll
            for (int j = 0; j < 4; ++j) {
                qa_[nj][j] = (__bf16)__builtin_amdgcn_exp2f(sa[nj][j] - ma);
                qb_[nj][j] = (__bf16)__builtin_amdgcn_exp2f(sb[nj][j] - mb);
            }

        f32x4 lta = {}, ltb = {};
        __builtin_amdgcn_s_setprio(1);
        #pragma unroll
        for (int nj = 0; nj < 4; ++nj) {
            lta = mfma16(qa_[nj], ones4, lta);
            ltb = mfma16(qb_[nj], ones4, ltb);
            #pragma unroll
            for (int ni = 0; ni < 4; ++ni) {
                bf16x4 bv = *(const bf16x4*)(Vtb + (ni * 16 + c) * 128 +
                                             (((2 * nj + ghalf) ^ c7) * 16) + gsub);
                oa[ni] = mfma16(qa_[nj], bv, oa[ni]);
                ob[ni] = mfma16(qb_[nj], bv, ob[ni]);
            }
        }
        __builtin_amdgcn_s_setprio(0);
        la += lta;
        lb += ltb;

        __syncthreads();
    }

    // --- in-LDS merge of the two KV halves ---
    f32x4 mja, mjb;
    #pragma unroll
    for (int j = 0; j < 4; ++j) {
        mja[j] = __shfl(ma, 4 * g + j);
        mjb[j] = __shfl(mb, 4 * g + j);
    }

    unsigned char* xbuf = smem + hw * 12288;
    if (hz == 1) {
        #pragma unroll
        for (int ni = 0; ni < 4; ++ni) {
            *(f32x4*)(xbuf + ni * 1024 + lane * 16) = oa[ni];
            *(f32x4*)(xbuf + (4 + ni) * 1024 + lane * 16) = ob[ni];
        }
        *(f32x4*)(xbuf + 8192 + 0 * 1024 + lane * 16) = mja;
        *(f32x4*)(xbuf + 8192 + 1 * 1024 + lane * 16) = la;
        *(f32x4*)(xbuf + 8192 + 2 * 1024 + lane * 16) = mjb;
        *(f32x4*)(xbuf + 8192 + 3 * 1024 + lane * 16) = lb;
    }
    __syncthreads();

    if (hz == 0) {
        f32x4 poa[4], pob[4];
        #pragma unroll
        for (int ni = 0; ni < 4; ++ni) {
            poa[ni] = *(const f32x4*)(xbuf + ni * 1024 + lane * 16);
            pob[ni] = *(const f32x4*)(xbuf + (4 + ni) * 1024 + lane * 16);
        }
        const f32x4 pmja = *(const f32x4*)(xbuf + 8192 + 0 * 1024 + lane * 16);
        const f32x4 pla  = *(const f32x4*)(xbuf + 8192 + 1 * 1024 + lane * 16);
        const f32x4 pmjb = *(const f32x4*)(xbuf + 8192 + 2 * 1024 + lane * 16);
        const f32x4 plb  = *(const f32x4*)(xbuf + 8192 + 3 * 1024 + lane * 16);

        const int b_ = bh >> 4, h = bh & 15;
        #pragma unroll
        for (int j = 0; j < 4; ++j) {
            {
                const float mx = fmaxf(mja[j], pmja[j]);
                const float e0 = __builtin_amdgcn_exp2f(mja[j] - mx);
                const float e1 = __builtin_amdgcn_exp2f(pmja[j] - mx);
                const float inv = 1.f / (e0 * la[j] + e1 * pla[j]);
                const int row = b_ * 2048 + q0 + 4 * g + j;
                #pragma unroll
                for (int ni = 0; ni < 4; ++ni) {
                    const int col = h * 64 + ni * 16 + c;
                    O[(size_t)row * 1024 + col] =
                        bfbits((e0 * oa[ni][j] + e1 * poa[ni][j]) * inv);
                }
            }
            {
                const float mx = fmaxf(mjb[j], pmjb[j]);
                const float e0 = __builtin_amdgcn_exp2f(mjb[j] - mx);
                const float e1 = __builtin_amdgcn_exp2f(pmjb[j] - mx);
                const float inv = 1.f / (e0 * lb[j] + e1 * plb[j]);
                const int row = b_ * 2048 + q0 + 16 + 4 * g + j;
                #pragma unroll
                for (int ni = 0; ni < 4; ++ni) {
                    const int col = h * 64 + ni * 16 + c;
                    O[(size_t)row * 1024 + col] =
                        bfbits((e0 * ob[ni][j] + e1 * pob[ni][j]) * inv);
                }
            }
        }
    }
}

extern "C" void kernel_launch(void* const* d_in, const int* in_sizes, int n_in,
                              void* d_out, int out_size, void* d_ws, size_t ws_size,
                              hipStream_t stream) {
    const float* x     = (const float*)d_in[0];
    const float* qkv_w = (const float*)d_in[1];
    const float* qkv_b = (const float*)d_in[2];
    const float* out_w = (const float*)d_in[3];
    const float* out_b = (const float*)d_in[4];
    float* out = (float*)d_out;

    char* ws = (char*)d_ws;
    unsigned short* ao   = (unsigned short*)(ws);                //  8 MB: attn out
    unsigned short* wqkv = (unsigned short*)(ws + (8u  << 20));  //  6 MB
    unsigned short* qb   = (unsigned short*)(ws + (16u << 20));  //  8 MB
    unsigned short* kb   = (unsigned short*)(ws + (24u << 20));  //  8 MB
    unsigned short* vtb  = (unsigned short*)(ws + (32u << 20));  //  8 MB
    unsigned short* wout = (unsigned short*)(ws + (40u << 20));  //  2 MB

    cvt_w<<<1024, 256, 0, stream>>>((const float4*)qkv_w, (const float4*)out_w,
                                    (ushort4*)wqkv, (ushort4*)wout);

    gemm_mfma<0><<<dim3(32, 24), 256, 0, stream>>>(x, nullptr, wqkv, qkv_b,
                                                   qb, kb, vtb, nullptr);

    attn_flash<<<dim3(16, 32), 512, 0, stream>>>(qb, kb, vtb, ao);

    gemm_mfma<1><<<dim3(32, 8), 256, 0, stream>>>(nullptr, ao, wout, out_b,
                                                  nullptr, nullptr, nullptr, out);
}

// Round 16
// 117.893 us; speedup vs baseline: 1.2371x; 1.2371x over previous
//
#include <hip/hip_runtime.h>
#include <hip/hip_bf16.h>

// MultiHeadAttention: x(2,2048,1024) fp32 -> out(2,2048,1024) fp32
// Pipeline: fused cvt->bf16; QKV GEMM (LDS-staged, 32x32x16 mfma) -> q,k,v^T;
// flash attn: 8 waves = 4 row-groups x 2 KV-halves in ONE block, in-LDS merge;
// out GEMM (BM=64 tile for 2 blocks/CU occupancy).
//
// ws layout:
//   [0,8M)    xb (bf16 x)  -> merged attn-out
//   [8,16M)   wqkv (6MB)
//   [16,24M)  q   [24,32M) k   [32,40M) vt   [40,42M) wout

typedef __bf16 bf16x8 __attribute__((ext_vector_type(8)));
typedef __bf16 bf16x4 __attribute__((ext_vector_type(4)));
typedef short short4v __attribute__((ext_vector_type(4)));
typedef float f32x4 __attribute__((ext_vector_type(4)));
typedef float f32x16 __attribute__((ext_vector_type(16)));

#define QSCALE 0.18033688011112042f  // 0.125 * log2(e): QK^T lands in log2 domain

__device__ __forceinline__ unsigned short bfbits(float f) {
    union { __bf16 h; unsigned short u; } cv;
    cv.h = (__bf16)f;
    return cv.u;
}

__device__ __forceinline__ f32x4 mfma16(bf16x4 a, bf16x4 b, f32x4 c) {
#if __has_builtin(__builtin_amdgcn_mfma_f32_16x16x16bf16_1k)
    union { bf16x4 h; short4v s; } ua, ub;
    ua.h = a; ub.h = b;
    return __builtin_amdgcn_mfma_f32_16x16x16bf16_1k(ua.s, ub.s, c, 0, 0, 0);
#else
    f32x4 d = c;
    asm volatile("v_mfma_f32_16x16x16_bf16 %0, %1, %2, %0"
                 : "+v"(d) : "v"(a), "v"(b));
    return d;
#endif
}

__device__ __forceinline__ void gl_lds16(const void* g, void* l) {
    __builtin_amdgcn_global_load_lds(
        (__attribute__((address_space(1))) const unsigned int*)g,
        (__attribute__((address_space(3))) unsigned int*)l, 16, 0, 0);
}

// Fused bf16 conversion into three regions.
__global__ void cvt_all(const float4* __restrict__ x,
                        const float4* __restrict__ wq,
                        const float4* __restrict__ wo,
                        ushort4* __restrict__ d0,
                        ushort4* __restrict__ d1,
                        ushort4* __restrict__ d2) {
    int i = blockIdx.x * blockDim.x + threadIdx.x;
    const int stride = gridDim.x * blockDim.x;
    for (; i < 2097152; i += stride) {
        float4 f;
        ushort4* d;
        int k;
        if (i < 1048576)       { f = x[i];           d = d0; k = i; }
        else if (i < 1835008)  { f = wq[i - 1048576]; d = d1; k = i - 1048576; }
        else                   { f = wo[i - 1835008]; d = d2; k = i - 1835008; }
        ushort4 o;
        o.x = bfbits(f.x); o.y = bfbits(f.y); o.z = bfbits(f.z); o.w = bfbits(f.w);
        d[k] = o;
    }
}

// C = A(M x 1024) @ W(N x 1024)^T + bias. BM x 128 block tile, 4 waves (2x2),
// wave tile (BM/2) x 64 via (BM/64) x 2 mfma_f32_32x32x16_bf16 frags.
// m97 staging (BK=64, global_load_lds w16, chunk^(row&7) swizzle, 2-barrier loop).
// 32x32 C/D layout (m74/m101): col=lane&31, row=(reg&3)+8*(reg>>2)+4*(lane>>5).
// MODE 0: BM=128, N=3072, scatter q (scaled QSCALE)/k/vt bf16.
// MODE 1: BM=64 (2 blocks/CU occupancy), N=1024, fp32 out.
template<int MODE>
__global__ __launch_bounds__(256, 3) void gemm_mfma(
    const unsigned short* __restrict__ A,
    const unsigned short* __restrict__ W,
    const float* __restrict__ bias,
    unsigned short* __restrict__ qo,
    unsigned short* __restrict__ ko,
    unsigned short* __restrict__ vto,
    float* __restrict__ fo) {
    constexpr int BM = (MODE == 0) ? 128 : 64;
    constexpr int MI = BM / 64;                      // 32x32 frags per wave in M
    __shared__ __attribute__((aligned(128))) unsigned char smem[32768];
    const int lane = threadIdx.x & 63;
    const int w = threadIdx.x >> 6;
    const int c5 = lane & 31, hi = lane >> 5;
    const int wr = w >> 1, wc = w & 1;
    const int row0 = blockIdx.x * BM;
    const int col0 = blockIdx.y * 128;

    const int rloc = lane >> 3;                      // 0..7
    const int csrc = ((lane & 7) ^ rloc) * 8;        // pre-swizzled source chunk (elements)

    f32x16 acc[MI][2] = {};

    const int ra = wr * (BM / 2) + c5;               // A rows for mi=0 (+32 for mi=1)
    const int rb = wc * 64 + c5;
    const int swa = ra & 7, swb = rb & 7;            // (r+32)&7 == r&7

    for (int kt = 0; kt < 1024; kt += 64) {
        #pragma unroll
        for (int i = 0; i < BM / 32; ++i) {
            const int r = i * 32 + w * 8 + rloc;
            gl_lds16(A + (size_t)(row0 + r) * 1024 + kt + csrc,
                     smem + i * 4096 + w * 1024);
        }
        #pragma unroll
        for (int i = 0; i < 4; ++i) {
            const int r = i * 32 + w * 8 + rloc;
            gl_lds16(W + (size_t)(col0 + r) * 1024 + kt + csrc,
                     smem + 16384 + i * 4096 + w * 1024);
        }
        __syncthreads();

        #pragma unroll
        for (int ks = 0; ks < 4; ++ks) {
            const int ch_a = ((2 * ks + hi) ^ swa) * 16;
            const int ch_b = ((2 * ks + hi) ^ swb) * 16;
            bf16x8 b0 = *(const bf16x8*)(smem + 16384 + rb * 128 + ch_b);
            bf16x8 b1 = *(const bf16x8*)(smem + 16384 + (rb + 32) * 128 + ch_b);
            #pragma unroll
            for (int mi = 0; mi < MI; ++mi) {
                bf16x8 a0 = *(const bf16x8*)(smem + (ra + mi * 32) * 128 + ch_a);
                acc[mi][0] = __builtin_amdgcn_mfma_f32_32x32x16_bf16(a0, b0, acc[mi][0], 0, 0, 0);
                acc[mi][1] = __builtin_amdgcn_mfma_f32_32x32x16_bf16(a0, b1, acc[mi][1], 0, 0, 0);
            }
        }
        __syncthreads();
    }

    #pragma unroll
    for (int mi = 0; mi < MI; ++mi) {
        #pragma unroll
        for (int ni = 0; ni < 2; ++ni) {
            const int col = col0 + wc * 64 + ni * 32 + c5;
            const float bv = bias[col];
            #pragma unroll
            for (int r = 0; r < 16; ++r) {
                const int row = row0 + wr * (BM / 2) + mi * 32 + (r & 3) + 8 * (r >> 2) + 4 * hi;
                float v = acc[mi][ni][r] + bv;
                if (MODE == 1) {
                    fo[(size_t)row * 1024 + col] = v;
                } else {
                    const int sec = col >> 10;          // 0=q 1=k 2=v
                    const int d = col & 1023;
                    const int h = d >> 6, dk = d & 63;
                    const int b_ = row >> 11, n = row & 2047;
                    const int bh = b_ * 16 + h;
                    if (sec == 0)
                        qo[((size_t)(bh * 2048 + n) << 6) + dk] = bfbits(v * QSCALE);
                    else if (sec == 1)
                        ko[((size_t)(bh * 2048 + n) << 6) + dk] = bfbits(v);
                    else
                        vto[(size_t)(bh * 64 + dk) * 2048 + n] = bfbits(v);
                }
            }
        }
    }
}

// Flash attention, split-KV internalized: 8 waves = 4 row-groups (hw) x 2 KV
// halves (hz); in-LDS merge; XCD swizzle. (Unchanged from R14 — proven.)
__global__ __launch_bounds__(512, 4) void attn_flash(
    const unsigned short* __restrict__ Q,
    const unsigned short* __restrict__ K,
    const unsigned short* __restrict__ Vt,
    unsigned short* __restrict__ O) {
    __shared__ __attribute__((aligned(128))) unsigned char smem[65536];
    const int lane = threadIdx.x & 63;
    const int w = threadIdx.x >> 6;          // 0..7
    const int hw = w & 3;                    // row-group
    const int hz = w >> 2;                   // KV half
    const int g = lane >> 4, c = lane & 15;
    const int c7 = c & 7;

    const int d = blockIdx.x + 16 * blockIdx.y;
    const int wv = (d & 7) * 64 + (d >> 3);
    const int bx = wv & 15;
    const int bh = wv >> 4;

    const int q0 = bx * 128 + hw * 32;
    const unsigned short* Qb = Q + (size_t)bh * 2048 * 64;
    const unsigned short* Kb = K + (size_t)bh * 2048 * 64;
    const unsigned short* Vb = Vt + (size_t)bh * 64 * 2048;

    const int rloc = lane >> 3;
    const int csrc = ((lane & 7) ^ (rloc & 7)) * 8;

    const int chunkKV0 = ((0 + g) ^ c7) * 16;
    const int chunkKV1 = ((4 + g) ^ c7) * 16;
    const int ghalf = g >> 1;
    const int gsub = (g & 1) * 8;

    unsigned char* Sbase = smem + hz * 32768;

    bf16x8 aq[2][2];
    #pragma unroll
    for (int qg = 0; qg < 2; ++qg)
        #pragma unroll
        for (int ks = 0; ks < 2; ++ks)
            aq[qg][ks] = *(const bf16x8*)(Qb + (size_t)(q0 + qg * 16 + c) * 64 + ks * 32 + 8 * g);

    f32x4 oa[4] = {}, ob[4] = {};
    f32x4 la = {}, lb = {};
    float ma = -1e30f, mb = -1e30f;

    bf16x4 ones4;
    #pragma unroll
    for (int i = 0; i < 4; ++i) ones4[i] = (__bf16)1.0f;

    const int gt0 = hz * 16;

    #pragma unroll
    for (int tt = 0; tt < 2; ++tt) {
        const int t = 2 * hw + tt;
        const int row = 8 * t + rloc;
        gl_lds16(Kb + (size_t)(gt0 * 64 + row) * 64 + csrc, Sbase + t * 1024);
        gl_lds16(Vb + (size_t)row * 2048 + gt0 * 64 + csrc, Sbase + 16384 + t * 1024);
    }
    __syncthreads();

    for (int t = 0; t < 16; ++t) {
        const int cur = t & 1;
        if (t + 1 < 16) {
            const int nb = cur ^ 1;
            const int gt = gt0 + t + 1;
            #pragma unroll
            for (int tt = 0; tt < 2; ++tt) {
                const int ti = 2 * hw + tt;
                const int row = 8 * ti + rloc;
                gl_lds16(Kb + (size_t)(gt * 64 + row) * 64 + csrc,
                         Sbase + nb * 8192 + ti * 1024);
                gl_lds16(Vb + (size_t)row * 2048 + gt * 64 + csrc,
                         Sbase + 16384 + nb * 8192 + ti * 1024);
            }
        }

        const unsigned char* Kt = Sbase + cur * 8192;
        const unsigned char* Vtb = Sbase + 16384 + cur * 8192;

        f32x4 sa[4] = {}, sb[4] = {};
        __builtin_amdgcn_s_setprio(1);
        #pragma unroll
        for (int nj = 0; nj < 4; ++nj) {
            bf16x8 bk0 = *(const bf16x8*)(Kt + nj * 2048 + c * 128 + chunkKV0);
            bf16x8 bk1 = *(const bf16x8*)(Kt + nj * 2048 + c * 128 + chunkKV1);
            sa[nj] = __builtin_amdgcn_mfma_f32_16x16x32_bf16(bk0, aq[0][0], sa[nj], 0, 0, 0);
            sa[nj] = __builtin_amdgcn_mfma_f32_16x16x32_bf16(bk1, aq[0][1], sa[nj], 0, 0, 0);
            sb[nj] = __builtin_amdgcn_mfma_f32_16x16x32_bf16(bk0, aq[1][0], sb[nj], 0, 0, 0);
            sb[nj] = __builtin_amdgcn_mfma_f32_16x16x32_bf16(bk1, aq[1][1], sb[nj], 0, 0, 0);
        }
        __builtin_amdgcn_s_setprio(0);

        float pa, pb;
        {
            float a0 = fmaxf(fmaxf(sa[0][0], sa[0][1]), fmaxf(sa[0][2], sa[0][3]));
            float a1 = fmaxf(fmaxf(sa[1][0], sa[1][1]), fmaxf(sa[1][2], sa[1][3]));
            float a2 = fmaxf(fmaxf(sa[2][0], sa[2][1]), fmaxf(sa[2][2], sa[2][3]));
            float a3 = fmaxf(fmaxf(sa[3][0], sa[3][1]), fmaxf(sa[3][2], sa[3][3]));
            pa = fmaxf(fmaxf(a0, a1), fmaxf(a2, a3));
            float b0 = fmaxf(fmaxf(sb[0][0], sb[0][1]), fmaxf(sb[0][2], sb[0][3]));
            float b1 = fmaxf(fmaxf(sb[1][0], sb[1][1]), fmaxf(sb[1][2], sb[1][3]));
            float b2 = fmaxf(fmaxf(sb[2][0], sb[2][1]), fmaxf(sb[2][2], sb[2][3]));
            float b3 = fmaxf(fmaxf(sb[3][0], sb[3][1]), fmaxf(sb[3][2], sb[3][3]));
            pb = fmaxf(fmaxf(b0, b1), fmaxf(b2, b3));
        }

        const bool trig = (pa > ma + 8.f) || (pb > mb + 8.f);
        if (__any((int)trig)) {
            float rm = pa;
            rm = fmaxf(rm, __shfl_xor(rm, 16));
            rm = fmaxf(rm, __shfl_xor(rm, 32));
            float mnew = fmaxf(ma, rm);
            float sc = __builtin_amdgcn_exp2f(ma - mnew);
            ma = mnew;
            #pragma unroll
            for (int j = 0; j < 4; ++j) {
                const float scj = __shfl(sc, 4 * g + j);
                la[j] *= scj;
                #pragma unroll
                for (int ni = 0; ni < 4; ++ni) oa[ni][j] *= scj;
            }
            rm = pb;
            rm = fmaxf(rm, __shfl_xor(rm, 16));
            rm = fmaxf(rm, __shfl_xor(rm, 32));
            mnew = fmaxf(mb, rm);
            sc = __builtin_amdgcn_exp2f(mb - mnew);
            mb = mnew;
            #pragma unroll
            for (int j = 0; j < 4; ++j) {
                const float scj = __shfl(sc, 4 * g + j);
                lb[j] *= scj;
                #pragma unroll
                for (int ni = 0; ni < 4; ++ni) ob[ni][j] *= scj;
            }
        }

        bf16x4 qa_[4], qb_[4];
        #pragma unroll
        for (int nj = 0; nj < 4; ++nj)
            #pragma unroll
            for (int j = 0; j < 4; ++j) {
                qa_[nj][j] = (__bf16)__builtin_amdgcn_exp2f(sa[nj][j] - ma);
                qb_[nj][j] = (__bf16)__builtin_amdgcn_exp2f(sb[nj][j] - mb);
            }

        f32x4 lta = {}, ltb = {};
        __builtin_amdgcn_s_setprio(1);
        #pragma unroll
        for (int nj = 0; nj < 4; ++nj) {
            lta = mfma16(qa_[nj], ones4, lta);
            ltb = mfma16(qb_[nj], ones4, ltb);
            #pragma unroll
            for (int ni = 0; ni < 4; ++ni) {
                bf16x4 bv = *(const bf16x4*)(Vtb + (ni * 16 + c) * 128 +
                                             (((2 * nj + ghalf) ^ c7) * 16) + gsub);
                oa[ni] = mfma16(qa_[nj], bv, oa[ni]);
                ob[ni] = mfma16(qb_[nj], bv, ob[ni]);
            }
        }
        __builtin_amdgcn_s_setprio(0);
        la += lta;
        lb += ltb;

        __syncthreads();
    }

    // --- in-LDS merge of the two KV halves ---
    f32x4 mja, mjb;
    #pragma unroll
    for (int j = 0; j < 4; ++j) {
        mja[j] = __shfl(ma, 4 * g + j);
        mjb[j] = __shfl(mb, 4 * g + j);
    }

    unsigned char* xbuf = smem + hw * 12288;
    if (hz == 1) {
        #pragma unroll
        for (int ni = 0; ni < 4; ++ni) {
            *(f32x4*)(xbuf + ni * 1024 + lane * 16) = oa[ni];
            *(f32x4*)(xbuf + (4 + ni) * 1024 + lane * 16) = ob[ni];
        }
        *(f32x4*)(xbuf + 8192 + 0 * 1024 + lane * 16) = mja;
        *(f32x4*)(xbuf + 8192 + 1 * 1024 + lane * 16) = la;
        *(f32x4*)(xbuf + 8192 + 2 * 1024 + lane * 16) = mjb;
        *(f32x4*)(xbuf + 8192 + 3 * 1024 + lane * 16) = lb;
    }
    __syncthreads();

    if (hz == 0) {
        f32x4 poa[4], pob[4];
        #pragma unroll
        for (int ni = 0; ni < 4; ++ni) {
            poa[ni] = *(const f32x4*)(xbuf + ni * 1024 + lane * 16);
            pob[ni] = *(const f32x4*)(xbuf + (4 + ni) * 1024 + lane * 16);
        }
        const f32x4 pmja = *(const f32x4*)(xbuf + 8192 + 0 * 1024 + lane * 16);
        const f32x4 pla  = *(const f32x4*)(xbuf + 8192 + 1 * 1024 + lane * 16);
        const f32x4 pmjb = *(const f32x4*)(xbuf + 8192 + 2 * 1024 + lane * 16);
        const f32x4 plb  = *(const f32x4*)(xbuf + 8192 + 3 * 1024 + lane * 16);

        const int b_ = bh >> 4, h = bh & 15;
        #pragma unroll
        for (int j = 0; j < 4; ++j) {
            {
                const float mx = fmaxf(mja[j], pmja[j]);
                const float e0 = __builtin_amdgcn_exp2f(mja[j] - mx);
                const float e1 = __builtin_amdgcn_exp2f(pmja[j] - mx);
                const float inv = 1.f / (e0 * la[j] + e1 * pla[j]);
                const int row = b_ * 2048 + q0 + 4 * g + j;
                #pragma unroll
                for (int ni = 0; ni < 4; ++ni) {
                    const int col = h * 64 + ni * 16 + c;
                    O[(size_t)row * 1024 + col] =
                        bfbits((e0 * oa[ni][j] + e1 * poa[ni][j]) * inv);
                }
            }
            {
                const float mx = fmaxf(mjb[j], pmjb[j]);
                const float e0 = __builtin_amdgcn_exp2f(mjb[j] - mx);
                const float e1 = __builtin_amdgcn_exp2f(pmjb[j] - mx);
                const float inv = 1.f / (e0 * lb[j] + e1 * plb[j]);
                const int row = b_ * 2048 + q0 + 16 + 4 * g + j;
                #pragma unroll
                for (int ni = 0; ni < 4; ++ni) {
                    const int col = h * 64 + ni * 16 + c;
                    O[(size_t)row * 1024 + col] =
                        bfbits((e0 * ob[ni][j] + e1 * pob[ni][j]) * inv);
                }
            }
        }
    }
}

extern "C" void kernel_launch(void* const* d_in, const int* in_sizes, int n_in,
                              void* d_out, int out_size, void* d_ws, size_t ws_size,
                              hipStream_t stream) {
    const float* x     = (const float*)d_in[0];
    const float* qkv_w = (const float*)d_in[1];
    const float* qkv_b = (const float*)d_in[2];
    const float* out_w = (const float*)d_in[3];
    const float* out_b = (const float*)d_in[4];
    float* out = (float*)d_out;

    char* ws = (char*)d_ws;
    unsigned short* xb   = (unsigned short*)(ws);                //  8 MB: x bf16 -> attn out
    unsigned short* wqkv = (unsigned short*)(ws + (8u  << 20));  //  6 MB
    unsigned short* qb   = (unsigned short*)(ws + (16u << 20));  //  8 MB
    unsigned short* kb   = (unsigned short*)(ws + (24u << 20));  //  8 MB
    unsigned short* vtb  = (unsigned short*)(ws + (32u << 20));  //  8 MB
    unsigned short* wout = (unsigned short*)(ws + (40u << 20));  //  2 MB

    cvt_all<<<2048, 256, 0, stream>>>((const float4*)x, (const float4*)qkv_w,
                                      (const float4*)out_w,
                                      (ushort4*)xb, (ushort4*)wqkv, (ushort4*)wout);

    gemm_mfma<0><<<dim3(32, 24), 256, 0, stream>>>(xb, wqkv, qkv_b, qb, kb, vtb, nullptr);

    unsigned short* ao = xb;  // xb no longer needed; attn writes merged O here
    attn_flash<<<dim3(16, 32), 512, 0, stream>>>(qb, kb, vtb, ao);

    gemm_mfma<1><<<dim3(64, 8), 256, 0, stream>>>(ao, wout, out_b,
                                                  nullptr, nullptr, nullptr, out);
}